// Round 2
// baseline (289.931 us; speedup 1.0000x reference)
//
#include <hip/hip_runtime.h>
#include <hip/hip_bf16.h>
#include <stdint.h>

typedef __bf16 bf16x8 __attribute__((ext_vector_type(8)));
typedef float f32x4 __attribute__((ext_vector_type(4)));
typedef unsigned short u16;

#define EPS_ 1e-6f
// sizes: T=8, N=1024, E=512 (256 static + 256 dynamic), REP=28, bs=224, FT=64

__device__ __forceinline__ void gload16(const void* g, void* l) {
  __builtin_amdgcn_global_load_lds((const __attribute__((address_space(1))) void*)g,
                                   (__attribute__((address_space(3))) void*)l,
                                   16, 0, 0);
}

__device__ __forceinline__ u16 f2bf(float v) {
  __hip_bfloat16 h = __float2bfloat16(v);
  return *reinterpret_cast<u16*>(&h);
}

// dv_inv_sqrt[t][n] = rsqrt(sum_e Gc[t,n,e] + EPS); one wave per (t,n) row.
__global__ void dv_kernel(const float* __restrict__ G, const float* __restrict__ G1,
                          float* __restrict__ dv) {
  const int row = blockIdx.x * 4 + (threadIdx.x >> 6);  // 0..8191 = t*1024+n
  const int lane = threadIdx.x & 63;
  const int t = row >> 10, n = row & 1023;
  const float4 g  = ((const float4*)(G  + (size_t)n * 256))[lane];
  const float4 g1 = ((const float4*)(G1 + ((size_t)t * 1024 + n) * 256))[lane];
  float s = g.x + g.y + g.z + g.w + g1.x + g1.y + g1.z + g1.w;
  #pragma unroll
  for (int off = 1; off < 64; off <<= 1) s += __shfl_xor(s, off);
  if (lane == 0) dv[row] = rsqrtf(s + EPS_);
}

// de_inv_sqrt[t][e] = rsqrt(sum_n Gc[t,n,e] + EPS); block per t, thread per e.
__global__ void de_kernel(const float* __restrict__ G, const float* __restrict__ G1,
                          float* __restrict__ de) {
  const int t = blockIdx.x;
  const int e = threadIdx.x;  // 0..511
  float s = 0.0f;
  if (e < 256) {
    const float* p = G + e;
    #pragma unroll 8
    for (int n = 0; n < 1024; ++n) s += p[(size_t)n * 256];
  } else {
    const float* p = G1 + (size_t)t * 1024 * 256 + (e - 256);
    #pragma unroll 8
    for (int n = 0; n < 1024; ++n) s += p[(size_t)n * 256];
  }
  de[t * 512 + e] = rsqrtf(s + EPS_);
}

// P[t][n][e] = bf16(Gc[t,n,e] * de_is[t,e] * dv_is[t,n])   (L = P P^T, symmetric)
__global__ void pack_kernel(const float* __restrict__ G, const float* __restrict__ G1,
                            const float* __restrict__ dv, const float* __restrict__ de,
                            u16* __restrict__ P) {
  const int idx = blockIdx.x * 256 + threadIdx.x;  // over t(3b) n(10b) e4(7b)
  const int e4 = idx & 127;
  const int n  = (idx >> 7) & 1023;
  const int t  = idx >> 17;
  const int e  = e4 * 4;
  float4 g;
  if (e < 256) g = *(const float4*)(G + (size_t)n * 256 + e);
  else         g = *(const float4*)(G1 + ((size_t)t * 1024 + n) * 256 + (e - 256));
  const float4 d = *(const float4*)(de + t * 512 + e);
  const float dvn = dv[t * 1024 + n];
  u16 o[4];
  o[0] = f2bf(g.x * d.x * dvn);
  o[1] = f2bf(g.y * d.y * dvn);
  o[2] = f2bf(g.z * d.z * dvn);
  o[3] = f2bf(g.w * d.w * dvn);
  *(ushort4*)(P + ((size_t)t * 1024 + n) * 512 + e) = *(ushort4*)o;
}

// XWT[t][j=(b*64+f)][m] = bf16(sum_k x[(t*28+b)*1024+m][k] * W[k][f] + bias[f])
// thread = one m-row; x row in registers; W/bias via wave-uniform scalar loads;
// stores: lanes are consecutive m -> 128B coalesced per f.
__global__ void xwt_kernel(const float* __restrict__ x, const float* __restrict__ w,
                           const float* __restrict__ bias, u16* __restrict__ xwt) {
  const int r = blockIdx.x * 256 + threadIdx.x;  // 0..229375
  const int t = r / 28672;
  const int rem = r - t * 28672;
  const int b = rem >> 10;
  const int m = rem & 1023;
  const float4* xr = (const float4*)(x + (size_t)r * 64);
  float4 xv[16];
  #pragma unroll
  for (int i = 0; i < 16; ++i) xv[i] = xr[i];
  float acc[64];
  #pragma unroll
  for (int f = 0; f < 64; ++f) acc[f] = bias[f];
  #pragma unroll
  for (int k = 0; k < 64; ++k) {
    const float xk = ((const float*)xv)[k];  // static index after full unroll
    #pragma unroll
    for (int f = 0; f < 64; ++f) acc[f] = fmaf(xk, w[k * 64 + f], acc[f]);
  }
  u16* o = xwt + ((size_t)t * 1792 + b * 64) * 1024 + m;
  #pragma unroll
  for (int f = 0; f < 64; ++f) o[(size_t)f << 10] = f2bf(acc[f]);
}

// 128x128-tile bf16 MFMA GEMM, A [M][K] row-major, B^T [N][K] row-major (m97 structure).
// MODE 0: L[t] = P[t] P[t]^T, K=512, bf16 out.   grid (64, 8)
// MODE 1: out[t][n][j] = sum_m L[t][n][m] XWT[t][j][m], K=1024, fp32 out scattered
//         to [(t*28+b)*1024+n]*64+f with j=b*64+f.   grid (112, 8)
template <int K, int MODE>
__global__ __launch_bounds__(256) void gemm_bt_kernel(
    const u16* __restrict__ Abase, const u16* __restrict__ Bbase,
    u16* __restrict__ Lw, float* __restrict__ Oo) {
  const int t = blockIdx.y;
  const int bx = blockIdx.x;
  const int row0 = (bx & 7) * 128;
  const int col0 = (bx >> 3) * 128;
  const size_t aoff = (MODE == 0) ? (size_t)t * 1024 * 512 : (size_t)t * 1024 * 1024;
  const size_t boff = (MODE == 0) ? (size_t)t * 1024 * 512 : (size_t)t * 1792 * 1024;
  const u16* A = Abase + aoff;
  const u16* B = Bbase + boff;

  __shared__ u16 As[128 * 32];
  __shared__ u16 Bs[128 * 32];

  const int tid = threadIdx.x;
  const int lane = tid & 63;
  const int wave = tid >> 6;
  const int wr = wave & 1, wc = wave >> 1;

  const int srow = tid >> 2;         // 0..63
  const int scol = (tid & 3) * 8;    // k-element offset (x8 bf16 = 16B)

  f32x4 acc[4][4] = {};

  const int l16 = lane & 15;
  const int lk = (lane >> 4) * 8;

  for (int kt = 0; kt < K / 32; ++kt) {
    const int kk = kt * 32 + scol;
    gload16(A + (size_t)(row0 + srow) * K + kk,       &As[srow * 32 + scol]);
    gload16(A + (size_t)(row0 + srow + 64) * K + kk,  &As[(srow + 64) * 32 + scol]);
    gload16(B + (size_t)(col0 + srow) * K + kk,       &Bs[srow * 32 + scol]);
    gload16(B + (size_t)(col0 + srow + 64) * K + kk,  &Bs[(srow + 64) * 32 + scol]);
    __syncthreads();  // waits vmcnt(0): LDS tiles ready
    bf16x8 af[4], bfr[4];
    #pragma unroll
    for (int i = 0; i < 4; ++i) {
      af[i]  = *(const bf16x8*)&As[(wr * 64 + i * 16 + l16) * 32 + lk];
      bfr[i] = *(const bf16x8*)&Bs[(wc * 64 + i * 16 + l16) * 32 + lk];
    }
    #pragma unroll
    for (int i = 0; i < 4; ++i)
      #pragma unroll
      for (int j = 0; j < 4; ++j)
        acc[i][j] = __builtin_amdgcn_mfma_f32_16x16x32_bf16(af[i], bfr[j], acc[i][j], 0, 0, 0);
    __syncthreads();  // protect LDS before next stage
  }

  const int l4 = lane >> 4;
  if constexpr (MODE == 0) {
    u16* Lt = Lw + (size_t)t * 1024 * 1024;
    #pragma unroll
    for (int i = 0; i < 4; ++i) {
      const int rbase = row0 + wr * 64 + i * 16 + l4 * 4;
      #pragma unroll
      for (int j = 0; j < 4; ++j) {
        const int col = col0 + wc * 64 + j * 16 + l16;
        #pragma unroll
        for (int r = 0; r < 4; ++r)
          Lt[(size_t)(rbase + r) * 1024 + col] = f2bf(acc[i][j][r]);
      }
    }
  } else {
    #pragma unroll
    for (int j = 0; j < 4; ++j) {
      const int jg = col0 + wc * 64 + j * 16 + l16;  // 0..1791
      float* Ot = Oo + (((size_t)t * 28 + (jg >> 6)) * 1024) * 64 + (jg & 63);
      #pragma unroll
      for (int i = 0; i < 4; ++i) {
        const int rbase = row0 + wr * 64 + i * 16 + l4 * 4;
        #pragma unroll
        for (int r = 0; r < 4; ++r)
          Ot[(size_t)(rbase + r) * 64] = acc[i][j][r];
      }
    }
  }
}

extern "C" void kernel_launch(void* const* d_in, const int* in_sizes, int n_in,
                              void* d_out, int out_size, void* d_ws, size_t ws_size,
                              hipStream_t stream) {
  const float* x  = (const float*)d_in[0];   // [224,1024,64]
  const float* G  = (const float*)d_in[1];   // [1024,256]
  const float* G1 = (const float*)d_in[2];   // [8,1024,256]
  const float* W  = (const float*)d_in[3];   // [64,64]
  const float* Bi = (const float*)d_in[4];   // [64]
  float* out = (float*)d_out;                // [224,1024,64] fp32

  // workspace layout (bytes): total 54,575,104
  char* ws = (char*)d_ws;
  float* dv = (float*)ws;                                  //  32 KB  [8][1024]
  float* de = (float*)(ws + 32768);                        //  16 KB  [8][512]
  u16*   P  = (u16*)(ws + 49152);                          //   8 MB  [8][1024][512]
  u16*   L  = (u16*)(ws + 49152 + 8388608);                //  16 MB  [8][1024][1024]
  u16*   XT = (u16*)(ws + 49152 + 8388608 + 16777216);     //  28 MB  [8][1792][1024]

  dv_kernel<<<2048, 256, 0, stream>>>(G, G1, dv);
  de_kernel<<<8, 512, 0, stream>>>(G, G1, de);
  pack_kernel<<<4096, 256, 0, stream>>>(G, G1, dv, de, P);
  gemm_bt_kernel<512, 0><<<dim3(64, 8), 256, 0, stream>>>(P, P, L, nullptr);
  xwt_kernel<<<896, 256, 0, stream>>>(x, W, Bi, XT);
  gemm_bt_kernel<1024, 1><<<dim3(112, 8), 256, 0, stream>>>(L, XT, nullptr, out);
}